// Round 3
// baseline (4910.703 us; speedup 1.0000x reference)
//
#include <hip/hip_runtime.h>
#include <math.h>

#define NC_   100000
#define ND_   100000
#define E_CNT 500000
#define L_CNT 100000
#define NH_   4
#define HD_   32

__device__ __forceinline__ float gelu_f(float x) {
    const float c0 = 0.7978845608028654f; // sqrt(2/pi)
    float x3 = x * x * x;
    return 0.5f * x * (1.0f + tanhf(c0 * (x + 0.044715f * x3)));
}

__device__ __forceinline__ void atomicMaxFloat(float* addr, float value) {
    if (value >= 0.0f) atomicMax((int*)addr, __float_as_int(value));
    else               atomicMin((unsigned int*)addr, __float_as_uint(value));
}

// ---- init kernels (graph-capture-safe) ----
__global__ __launch_bounds__(256) void fill_zero4(float4* __restrict__ p, int n4) {
    int i = blockIdx.x * 256 + threadIdx.x;
    if (i < n4) p[i] = make_float4(0.f, 0.f, 0.f, 0.f);
}
__global__ __launch_bounds__(256) void init_softmax(float* __restrict__ amax,
                                                    float* __restrict__ den, int n) {
    int i = blockIdx.x * 256 + threadIdx.x;
    if (i < n) { amax[i] = -INFINITY; den[i] = 0.f; }
}

// Fused per-type weight blocks (Wcat: 128 rows x 384 cols, bias row at 128):
//   cols [0,128): qW+qb | [128,256): kW@blockdiag(arel) | [256,384): vW@blockdiag(mrel)
__global__ void fuse_weights(const float* __restrict__ qW, const float* __restrict__ qb,
                             const float* __restrict__ kW, const float* __restrict__ kb,
                             const float* __restrict__ vW, const float* __restrict__ vb,
                             const float* __restrict__ arel, const float* __restrict__ mrel,
                             float* __restrict__ WcatC, float* __restrict__ WcatD)
{
    int i  = blockIdx.x;   // 0..128 (128 == bias row)
    int t  = blockIdx.y;   // node type (== relation whose src is t)
    int oc = threadIdx.x;  // 0..383
    float* Wcat = t ? WcatD : WcatC;
    float val;
    if (oc < 128) {
        val = (i < 128) ? qW[(t * 128 + i) * 128 + oc] : qb[t * 128 + oc];
    } else {
        int which = (oc >= 256);
        int cc = oc - (which ? 256 : 128);
        int h = cc >> 5, e = cc & 31;
        const float* W = which ? vW : kW;
        const float* b = which ? vb : kb;
        const float* R = (which ? mrel : arel) + (size_t)(t * NH_ + h) * HD_ * HD_ + e;
        float s = 0.f;
        if (i < 128) {
            const float* wrow = W + (size_t)(t * 128 + i) * 128 + h * 32;
            #pragma unroll
            for (int d2 = 0; d2 < 32; d2++) s += wrow[d2] * R[d2 * 32];
        } else {
            const float* brow = b + t * 128 + h * 32;
            #pragma unroll
            for (int d2 = 0; d2 < 32; d2++) s += brow[d2] * R[d2 * 32];
        }
        val = s;
    }
    Wcat[(size_t)((i < 128) ? i : 128) * 384 + oc] = val;
}

// fp32 tiled GEMM: C[M,N] = act(A[M,128] @ B[128,N] + bias), tile 64x64, BK=16,
// 4x4 register blocking. PREACT=1: gelu on A load. POST=1: C = relu(g*v + (1-g)*resid);
// resid may alias C (same-thread same-element RMW).
template<int PREACT, int POST>
__global__ __launch_bounds__(256)
void gemm_tiled(const float* __restrict__ A, int lda,
                const float* __restrict__ B, int ldb,
                const float* __restrict__ bias,
                float* __restrict__ C, int ldc,
                int M,
                const float* __restrict__ resid,
                const float* __restrict__ skipv)
{
    __shared__ float As[16][68];
    __shared__ float Bs[16][68];
    int tid = threadIdx.x;
    int tx = tid & 15, ty = tid >> 4;
    int bm = blockIdx.x * 64;
    int bn = blockIdx.y * 64;
    float acc[4][4] = {};
    int am  = tid >> 2;
    int ak  = (tid & 3) << 2;
    int bk  = tid >> 4;
    int bn4 = (tid & 15) << 2;
    int arow = bm + am;
    bool avalid = arow < M;
    const float* aptr = A + (size_t)arow * lda + ak;
    const float* bptr = B + (size_t)bk * ldb + bn + bn4;

    for (int k0 = 0; k0 < 128; k0 += 16) {
        float4 av = make_float4(0.f, 0.f, 0.f, 0.f);
        if (avalid) av = *(const float4*)(aptr + k0);
        if (PREACT) { av.x = gelu_f(av.x); av.y = gelu_f(av.y); av.z = gelu_f(av.z); av.w = gelu_f(av.w); }
        float4 bv = *(const float4*)(bptr + (size_t)k0 * ldb);
        __syncthreads();
        As[ak + 0][am] = av.x; As[ak + 1][am] = av.y; As[ak + 2][am] = av.z; As[ak + 3][am] = av.w;
        *(float4*)&Bs[bk][bn4] = bv;
        __syncthreads();
        #pragma unroll
        for (int kk = 0; kk < 16; kk++) {
            float a0 = As[kk][(ty << 2) + 0], a1 = As[kk][(ty << 2) + 1];
            float a2 = As[kk][(ty << 2) + 2], a3 = As[kk][(ty << 2) + 3];
            float b0 = Bs[kk][(tx << 2) + 0], b1 = Bs[kk][(tx << 2) + 1];
            float b2 = Bs[kk][(tx << 2) + 2], b3 = Bs[kk][(tx << 2) + 3];
            acc[0][0] += a0 * b0; acc[0][1] += a0 * b1; acc[0][2] += a0 * b2; acc[0][3] += a0 * b3;
            acc[1][0] += a1 * b0; acc[1][1] += a1 * b1; acc[1][2] += a1 * b2; acc[1][3] += a1 * b3;
            acc[2][0] += a2 * b0; acc[2][1] += a2 * b1; acc[2][2] += a2 * b2; acc[2][3] += a2 * b3;
            acc[3][0] += a3 * b0; acc[3][1] += a3 * b1; acc[3][2] += a3 * b2; acc[3][3] += a3 * b3;
        }
    }

    float g = 0.f, omg = 0.f;
    if (POST) { float sv = skipv[0]; g = 1.0f / (1.0f + expf(-sv)); omg = 1.0f - g; }
    #pragma unroll
    for (int i = 0; i < 4; i++) {
        int m = bm + (ty << 2) + i;
        if (m >= M) continue;
        #pragma unroll
        for (int j = 0; j < 4; j++) {
            int n = bn + (tx << 2) + j;
            float v = acc[i][j] + bias[n];
            if (POST) {
                v = g * v + omg * resid[(size_t)m * ldc + n];
                v = fmaxf(v, 0.0f);
            }
            C[(size_t)m * ldc + n] = v;
        }
    }
}

// Pass 1: per-edge per-head score + atomic segment max. q_d,k_s: [N,128].
__global__ __launch_bounds__(256)
void edge_score(const int* __restrict__ src, const int* __restrict__ dst,
                const float* __restrict__ q_d, const float* __restrict__ k_s,
                const float* __restrict__ prel,
                float* __restrict__ a_e, float* __restrict__ amax)
{
    int gid = blockIdx.x * 256 + threadIdx.x;
    int e = gid >> 5, lane = gid & 31;
    if (e >= E_CNT) return;
    int s = src[e], d = dst[e];
    float4 qv = *(const float4*)(q_d + (size_t)d * 128 + lane * 4);
    float4 kv = *(const float4*)(k_s + (size_t)s * 128 + lane * 4);
    float dotv = qv.x * kv.x + qv.y * kv.y + qv.z * kv.z + qv.w * kv.w;
    dotv += __shfl_down(dotv, 4, 8);
    dotv += __shfl_down(dotv, 2, 8);
    dotv += __shfl_down(dotv, 1, 8);
    if ((lane & 7) == 0) {
        int h = lane >> 3;
        float aval = dotv * prel[h] * 0.17677669529663687f; // 1/sqrt(32)
        a_e[(size_t)e * 4 + h] = aval;
        atomicMaxFloat(&amax[(size_t)d * 4 + h], aval);
    }
}

// Pass 2: ex = exp(a - amax[dst]) in-place; den += ex.
__global__ __launch_bounds__(256)
void edge_expden(const int* __restrict__ dst, const float* __restrict__ amax,
                 float* __restrict__ a_e, float* __restrict__ den)
{
    int gid = blockIdx.x * 256 + threadIdx.x;
    int e = gid >> 2, h = gid & 3;
    if (e >= E_CNT) return;
    int d = dst[e];
    float ex = expf(a_e[gid] - amax[d * 4 + h]);
    a_e[gid] = ex;
    unsafeAtomicAdd(&den[d * 4 + h], ex);
}

// Pass 3: out[dst] += v_s[src] * (ex / (den[dst] + 1e-16)). v_s: [N,128].
__global__ __launch_bounds__(256)
void edge_scatter(const int* __restrict__ src, const int* __restrict__ dst,
                  const float* __restrict__ v_s,
                  const float* __restrict__ a_e, const float* __restrict__ den,
                  float* __restrict__ outd)
{
    int gid = blockIdx.x * 256 + threadIdx.x;
    int e = gid >> 5, lane = gid & 31;
    if (e >= E_CNT) return;
    int s = src[e], d = dst[e];
    int h = lane >> 3;
    float alpha = a_e[(size_t)e * 4 + h] / (den[d * 4 + h] + 1e-16f);
    float4 vv = *(const float4*)(v_s + (size_t)s * 128 + lane * 4);
    float* op = outd + (size_t)d * 128 + lane * 4;
    unsafeAtomicAdd(op + 0, vv.x * alpha);
    unsafeAtomicAdd(op + 1, vv.y * alpha);
    unsafeAtomicAdd(op + 2, vv.z * alpha);
    unsafeAtomicAdd(op + 3, vv.w * alpha);
}

// Final scoring: 16 lanes per pair, 64-dim dot, clip to [-10,10].
__global__ __launch_bounds__(256)
void score_pairs(const int* __restrict__ ic, const int* __restrict__ id,
                 const float* __restrict__ zC, const float* __restrict__ zD,
                 float* __restrict__ out)
{
    int gid = blockIdx.x * 256 + threadIdx.x;
    int p = gid >> 4, lane = gid & 15;
    if (p >= L_CNT) return;
    int c = ic[p], d = id[p];
    float4 a = *(const float4*)(zC + (size_t)c * 64 + lane * 4);
    float4 b = *(const float4*)(zD + (size_t)d * 64 + lane * 4);
    float s = a.x * b.x + a.y * b.y + a.z * b.z + a.w * b.w;
    s += __shfl_down(s, 8, 16);
    s += __shfl_down(s, 4, 16);
    s += __shfl_down(s, 2, 16);
    s += __shfl_down(s, 1, 16);
    if (lane == 0) out[p] = fminf(10.0f, fmaxf(-10.0f, s));
}

extern "C" void kernel_launch(void* const* d_in, const int* in_sizes, int n_in,
                              void* d_out, int out_size, void* d_ws, size_t ws_size,
                              hipStream_t stream)
{
    // Persistent node states live IN the emb input buffers (harness restores
    // d_in from pristine copies before every timed launch, so mutation is safe).
    float* xC = (float*)d_in[0];
    float* xD = (float*)d_in[1];
    const float* kW   = (const float*)d_in[2];
    const float* kb   = (const float*)d_in[3];
    const float* qW   = (const float*)d_in[4];
    const float* qb   = (const float*)d_in[5];
    const float* vW   = (const float*)d_in[6];
    const float* vb   = (const float*)d_in[7];
    const float* aW   = (const float*)d_in[8];
    const float* ab   = (const float*)d_in[9];
    const float* skip = (const float*)d_in[10];
    const float* arel = (const float*)d_in[11];
    const float* mrel = (const float*)d_in[12];
    const float* prel = (const float*)d_in[13];
    const float* outW = (const float*)d_in[14];
    const float* outb = (const float*)d_in[15];
    const int* ei_cd  = (const int*)d_in[16];
    const int* ei_dc  = (const int*)d_in[17];
    const int* eli    = (const int*)d_in[18];

    // Workspace: 41.3M floats = 165 MB total.
    float* ws = (float*)d_ws;
    size_t off = 0;
    float* kvb   = ws + off; off += (size_t)NC_ * 128;   // 12.8M (k, then v, per relation)
    float* qb_   = ws + off; off += (size_t)ND_ * 128;   // 12.8M (dst q)
    float* outa  = ws + off; off += (size_t)NC_ * 128;   // 12.8M (dst accumulator)
    float* a_e   = ws + off; off += (size_t)E_CNT * 4;   //  2.0M
    float* amax  = ws + off; off += (size_t)NC_ * 4;     //  0.4M
    float* den   = ws + off; off += (size_t)NC_ * 4;     //  0.4M
    float* WcatC = ws + off; off += (size_t)129 * 384;
    float* WcatD = ws + off; off += (size_t)129 * 384;
    float* zC = kvb;   // reuse after last edge phase (needs 6.4M each)
    float* zD = qb_;

    const int gridM = (NC_ + 63) / 64;          // 1563
    const int gZero = (NC_ * 32 + 255) / 256;   // 12500 float4 fills
    const int gSmax = (NC_ * 4 + 255) / 256;

    for (int l = 0; l < 2; l++) {
        const float* aWl = aW + (size_t)l * 2 * 128 * 128;
        const float* abl = ab + (size_t)l * 2 * 128;

        fuse_weights<<<dim3(129, 2), 384, 0, stream>>>(
            qW + (size_t)l * 2 * 128 * 128, qb + (size_t)l * 2 * 128,
            kW + (size_t)l * 2 * 128 * 128, kb + (size_t)l * 2 * 128,
            vW + (size_t)l * 2 * 128 * 128, vb + (size_t)l * 2 * 128,
            arel + (size_t)l * 2 * NH_ * HD_ * HD_,
            mrel + (size_t)l * 2 * NH_ * HD_ * HD_, WcatC, WcatD);

        // ---- relation 0: C -> D ----
        gemm_tiled<0, 0><<<dim3(gridM, 2), 256, 0, stream>>>(          // kC
            xC, 128, WcatC + 128, 384, WcatC + 128 * 384 + 128, kvb, 128, NC_, nullptr, nullptr);
        gemm_tiled<0, 0><<<dim3(gridM, 2), 256, 0, stream>>>(          // qD
            xD, 128, WcatD, 384, WcatD + 128 * 384, qb_, 128, ND_, nullptr, nullptr);
        init_softmax<<<gSmax, 256, 0, stream>>>(amax, den, ND_ * 4);
        edge_score  <<<62500, 256, 0, stream>>>(ei_cd, ei_cd + E_CNT, qb_, kvb,
                                                prel + (l * 2 + 0) * 4, a_e, amax);
        edge_expden <<<7813, 256, 0, stream>>>(ei_cd + E_CNT, amax, a_e, den);
        gemm_tiled<0, 0><<<dim3(gridM, 2), 256, 0, stream>>>(          // vC (overwrite kC)
            xC, 128, WcatC + 256, 384, WcatC + 128 * 384 + 256, kvb, 128, NC_, nullptr, nullptr);
        fill_zero4<<<gZero, 256, 0, stream>>>((float4*)outa, ND_ * 32);
        edge_scatter<<<62500, 256, 0, stream>>>(ei_cd, ei_cd + E_CNT, kvb, a_e, den, outa);

        // ---- relation 1 score phase (from OLD x, before epilogue D) ----
        gemm_tiled<0, 0><<<dim3(gridM, 2), 256, 0, stream>>>(          // kD
            xD, 128, WcatD + 128, 384, WcatD + 128 * 384 + 128, kvb, 128, ND_, nullptr, nullptr);
        gemm_tiled<0, 0><<<dim3(gridM, 2), 256, 0, stream>>>(          // qC
            xC, 128, WcatC, 384, WcatC + 128 * 384, qb_, 128, NC_, nullptr, nullptr);
        init_softmax<<<gSmax, 256, 0, stream>>>(amax, den, NC_ * 4);
        edge_score  <<<62500, 256, 0, stream>>>(ei_dc, ei_dc + E_CNT, qb_, kvb,
                                                prel + (l * 2 + 1) * 4, a_e, amax);
        edge_expden <<<7813, 256, 0, stream>>>(ei_dc + E_CNT, amax, a_e, den);
        gemm_tiled<0, 0><<<dim3(gridM, 2), 256, 0, stream>>>(          // vD (old xD)
            xD, 128, WcatD + 256, 384, WcatD + 128 * 384 + 256, kvb, 128, ND_, nullptr, nullptr);

        // epilogue D: xD = relu(g*(gelu(outD)@aW_D+ab_D) + (1-g)*xD)  [in-place resid]
        gemm_tiled<1, 1><<<dim3(gridM, 2), 256, 0, stream>>>(
            outa, 128, aWl + 128 * 128, 128, abl + 128, xD, 128, ND_, xD, skip + l * 2 + 1);

        // ---- relation 1 scatter + epilogue C ----
        fill_zero4<<<gZero, 256, 0, stream>>>((float4*)outa, NC_ * 32);
        edge_scatter<<<62500, 256, 0, stream>>>(ei_dc, ei_dc + E_CNT, kvb, a_e, den, outa);
        gemm_tiled<1, 1><<<dim3(gridM, 2), 256, 0, stream>>>(
            outa, 128, aWl, 128, abl, xC, 128, NC_, xC, skip + l * 2 + 0);
    }

    // final projections z = x @ outW + outb  ([N,128] @ [128,64])
    gemm_tiled<0, 0><<<dim3(gridM, 1), 256, 0, stream>>>(
        xC, 128, outW, 64, outb, zC, 64, NC_, nullptr, nullptr);
    gemm_tiled<0, 0><<<dim3(gridM, 1), 256, 0, stream>>>(
        xD, 128, outW + 128 * 64, 64, outb + 64, zD, 64, ND_, nullptr, nullptr);

    score_pairs<<<(L_CNT * 16 + 255) / 256, 256, 0, stream>>>(
        eli, eli + L_CNT, zC, zD, (float*)d_out);
}

// Round 4
// 1509.288 us; speedup vs baseline: 3.2537x; 3.2537x over previous
//
#include <hip/hip_runtime.h>
#include <math.h>

#define NC_   100000
#define ND_   100000
#define NN_   100000   // == NC_ == ND_ (used for shared-size buffers)
#define E_CNT 500000
#define L_CNT 100000
#define NH_   4
#define HD_   32

__device__ __forceinline__ float gelu_f(float x) {
    const float c0 = 0.7978845608028654f; // sqrt(2/pi)
    float x3 = x * x * x;
    return 0.5f * x * (1.0f + tanhf(c0 * (x + 0.044715f * x3)));
}

// ======================= CSR build (counting sort by dst) =======================
__global__ __launch_bounds__(256) void fill0_int(int* __restrict__ p, int n) {
    int i = blockIdx.x * 256 + threadIdx.x;
    if (i < n) p[i] = 0;
}

__global__ __launch_bounds__(256) void count_dst(const int* __restrict__ dst,
                                                 int* __restrict__ cnt) {
    int e = blockIdx.x * 256 + threadIdx.x;
    if (e < E_CNT) atomicAdd(&cnt[dst[e]], 1);
}

// scan_a: 98 blocks x 256 threads, 4 consecutive elems/thread (1024/block).
// Writes block-local exclusive prefix into excl[], block total into partials[b].
__global__ __launch_bounds__(256) void scan_a(const int* __restrict__ cnt,
                                              int* __restrict__ excl,
                                              int* __restrict__ partials) {
    __shared__ int sd[256];
    int b = blockIdx.x, t = threadIdx.x;
    int base = b * 1024 + t * 4;
    int v0 = (base + 0 < NN_) ? cnt[base + 0] : 0;
    int v1 = (base + 1 < NN_) ? cnt[base + 1] : 0;
    int v2 = (base + 2 < NN_) ? cnt[base + 2] : 0;
    int v3 = (base + 3 < NN_) ? cnt[base + 3] : 0;
    int tsum = v0 + v1 + v2 + v3;
    sd[t] = tsum; __syncthreads();
    for (int off = 1; off < 256; off <<= 1) {
        int x = (t >= off) ? sd[t - off] : 0;
        __syncthreads();
        sd[t] += x;
        __syncthreads();
    }
    int excl_t = sd[t] - tsum;
    if (t == 255) partials[b] = sd[t];
    int r = excl_t;
    if (base + 0 < NN_) excl[base + 0] = r; r += v0;
    if (base + 1 < NN_) excl[base + 1] = r; r += v1;
    if (base + 2 < NN_) excl[base + 2] = r; r += v2;
    if (base + 3 < NN_) excl[base + 3] = r;
}

// scan_b: single block, exclusive scan of 98 partials in-place.
__global__ __launch_bounds__(128) void scan_b(int* __restrict__ partials) {
    __shared__ int sd[128];
    int t = threadIdx.x;
    int orig = (t < 98) ? partials[t] : 0;
    sd[t] = orig; __syncthreads();
    for (int off = 1; off < 128; off <<= 1) {
        int x = (t >= off) ? sd[t - off] : 0;
        __syncthreads();
        sd[t] += x;
        __syncthreads();
    }
    if (t < 98) partials[t] = sd[t] - orig;
}

// scan_c: add block offsets; row_ptr finalized in-place; also init cursor copy.
__global__ __launch_bounds__(256) void scan_c(int* __restrict__ row_ptr,
                                              const int* __restrict__ partials,
                                              int* __restrict__ cursor) {
    int b = blockIdx.x, t = threadIdx.x;
    int base = b * 1024 + t * 4;
    int add = partials[b];
    #pragma unroll
    for (int j = 0; j < 4; j++) {
        int i = base + j;
        if (i < NN_) { int v = row_ptr[i] + add; row_ptr[i] = v; cursor[i] = v; }
    }
    if (b == 0 && t == 0) row_ptr[NN_] = E_CNT;
}

__global__ __launch_bounds__(256) void scatter_edges(const int* __restrict__ src,
                                                     const int* __restrict__ dst,
                                                     int* __restrict__ cursor,
                                                     int* __restrict__ srcs) {
    int e = blockIdx.x * 256 + threadIdx.x;
    if (e >= E_CNT) return;
    int pos = atomicAdd(&cursor[dst[e]], 1);
    srcs[pos] = src[e];
}

// ======================= weight fusion =======================
// Wcat: 128 rows x 384 cols, bias row at 128:
//   cols [0,128): qW+qb | [128,256): kW@blockdiag(arel) | [256,384): vW@blockdiag(mrel)
__global__ void fuse_weights(const float* __restrict__ qW, const float* __restrict__ qb,
                             const float* __restrict__ kW, const float* __restrict__ kb,
                             const float* __restrict__ vW, const float* __restrict__ vb,
                             const float* __restrict__ arel, const float* __restrict__ mrel,
                             float* __restrict__ WcatC, float* __restrict__ WcatD)
{
    int i  = blockIdx.x;   // 0..128 (128 == bias row)
    int t  = blockIdx.y;
    int oc = threadIdx.x;  // 0..383
    float* Wcat = t ? WcatD : WcatC;
    float val;
    if (oc < 128) {
        val = (i < 128) ? qW[(t * 128 + i) * 128 + oc] : qb[t * 128 + oc];
    } else {
        int which = (oc >= 256);
        int cc = oc - (which ? 256 : 128);
        int h = cc >> 5, e = cc & 31;
        const float* W = which ? vW : kW;
        const float* b = which ? vb : kb;
        const float* R = (which ? mrel : arel) + (size_t)(t * NH_ + h) * HD_ * HD_ + e;
        float s = 0.f;
        if (i < 128) {
            const float* wrow = W + (size_t)(t * 128 + i) * 128 + h * 32;
            #pragma unroll
            for (int d2 = 0; d2 < 32; d2++) s += wrow[d2] * R[d2 * 32];
        } else {
            const float* brow = b + t * 128 + h * 32;
            #pragma unroll
            for (int d2 = 0; d2 < 32; d2++) s += brow[d2] * R[d2 * 32];
        }
        val = s;
    }
    Wcat[(size_t)((i < 128) ? i : 128) * 384 + oc] = val;
}

// ======================= fp32 tiled GEMM =======================
// C[M,N] = act(A[M,128] @ B[128,N] + bias); tile 64x64, BK=16, 4x4 reg blocking.
// PREACT: gelu on A load. POST: C = relu(g*v + (1-g)*resid) (resid may alias C).
template<int PREACT, int POST>
__global__ __launch_bounds__(256)
void gemm_tiled(const float* __restrict__ A, int lda,
                const float* __restrict__ B, int ldb,
                const float* __restrict__ bias,
                float* __restrict__ C, int ldc,
                int M,
                const float* __restrict__ resid,
                const float* __restrict__ skipv)
{
    __shared__ float As[16][68];
    __shared__ float Bs[16][68];
    int tid = threadIdx.x;
    int tx = tid & 15, ty = tid >> 4;
    int bm = blockIdx.x * 64;
    int bn = blockIdx.y * 64;
    float acc[4][4] = {};
    int am  = tid >> 2;
    int ak  = (tid & 3) << 2;
    int bk  = tid >> 4;
    int bn4 = (tid & 15) << 2;
    int arow = bm + am;
    bool avalid = arow < M;
    const float* aptr = A + (size_t)arow * lda + ak;
    const float* bptr = B + (size_t)bk * ldb + bn + bn4;

    for (int k0 = 0; k0 < 128; k0 += 16) {
        float4 av = make_float4(0.f, 0.f, 0.f, 0.f);
        if (avalid) av = *(const float4*)(aptr + k0);
        if (PREACT) { av.x = gelu_f(av.x); av.y = gelu_f(av.y); av.z = gelu_f(av.z); av.w = gelu_f(av.w); }
        float4 bv = *(const float4*)(bptr + (size_t)k0 * ldb);
        __syncthreads();
        As[ak + 0][am] = av.x; As[ak + 1][am] = av.y; As[ak + 2][am] = av.z; As[ak + 3][am] = av.w;
        *(float4*)&Bs[bk][bn4] = bv;
        __syncthreads();
        #pragma unroll
        for (int kk = 0; kk < 16; kk++) {
            float a0 = As[kk][(ty << 2) + 0], a1 = As[kk][(ty << 2) + 1];
            float a2 = As[kk][(ty << 2) + 2], a3 = As[kk][(ty << 2) + 3];
            float b0 = Bs[kk][(tx << 2) + 0], b1 = Bs[kk][(tx << 2) + 1];
            float b2 = Bs[kk][(tx << 2) + 2], b3 = Bs[kk][(tx << 2) + 3];
            acc[0][0] += a0 * b0; acc[0][1] += a0 * b1; acc[0][2] += a0 * b2; acc[0][3] += a0 * b3;
            acc[1][0] += a1 * b0; acc[1][1] += a1 * b1; acc[1][2] += a1 * b2; acc[1][3] += a1 * b3;
            acc[2][0] += a2 * b0; acc[2][1] += a2 * b1; acc[2][2] += a2 * b2; acc[2][3] += a2 * b3;
            acc[3][0] += a3 * b0; acc[3][1] += a3 * b1; acc[3][2] += a3 * b2; acc[3][3] += a3 * b3;
        }
    }

    float g = 0.f, omg = 0.f;
    if (POST) { float sv = skipv[0]; g = 1.0f / (1.0f + expf(-sv)); omg = 1.0f - g; }
    #pragma unroll
    for (int i = 0; i < 4; i++) {
        int m = bm + (ty << 2) + i;
        if (m >= M) continue;
        #pragma unroll
        for (int j = 0; j < 4; j++) {
            int n = bn + (tx << 2) + j;
            float v = acc[i][j] + bias[n];
            if (POST) {
                v = g * v + omg * resid[(size_t)m * ldc + n];
                v = fmaxf(v, 0.0f);
            }
            C[(size_t)m * ldc + n] = v;
        }
    }
}

// ======================= fused attention gather =======================
// One wave (64 lanes) per dst node. qo: [Nd,128] holds dst q on entry, final
// attention output on exit (safe: each wave touches only its own row).
// kv: [Ns,256] = [krel(128) | vrel(128)]. Online softmax per head; no atomics.
__global__ __launch_bounds__(256)
void attn_gather(const int* __restrict__ row_ptr, const int* __restrict__ srcs,
                 float* __restrict__ qo, const float* __restrict__ kv,
                 const float* __restrict__ prel, int ndst)
{
    int wave = (blockIdx.x * 256 + threadIdx.x) >> 6;
    int lane = threadIdx.x & 63;
    if (wave >= ndst) return;
    int d = wave;
    int beg = row_ptr[d], end = row_ptr[d + 1];
    int h = lane >> 4;                 // head = 16-lane group; dims [lane*2, lane*2+1]
    float pr = prel[h] * 0.17677669529663687f;  // prel / sqrt(32)
    float2 qv = *(const float2*)(qo + (size_t)d * 128 + lane * 2);
    float m = -1.0e30f, l = 0.f;
    float2 acc = make_float2(0.f, 0.f);
    for (int i = beg; i < end; i++) {
        int s = srcs[i];
        const float* row = kv + (size_t)s * 256;
        float2 kvv = *(const float2*)(row + lane * 2);
        float2 vv  = *(const float2*)(row + 128 + lane * 2);
        float part = qv.x * kvv.x + qv.y * kvv.y;
        part += __shfl_xor(part, 8);
        part += __shfl_xor(part, 4);
        part += __shfl_xor(part, 2);
        part += __shfl_xor(part, 1);   // all 16 lanes of head h now hold head-h dot
        float a = part * pr;
        float mn = fmaxf(m, a);
        float scale = expf(m - mn);    // first iter: exp(-1e30) -> 0
        float p = expf(a - mn);
        l = l * scale + p;
        acc.x = acc.x * scale + p * vv.x;
        acc.y = acc.y * scale + p * vv.y;
        m = mn;
    }
    float inv = 1.f / (l + 1e-16f);
    if (beg == end) inv = 0.f;         // no edges -> exact zero
    *(float2*)(qo + (size_t)d * 128 + lane * 2) = make_float2(acc.x * inv, acc.y * inv);
}

// ======================= final scoring =======================
__global__ __launch_bounds__(256)
void score_pairs(const int* __restrict__ ic, const int* __restrict__ id,
                 const float* __restrict__ zC, const float* __restrict__ zD,
                 float* __restrict__ out)
{
    int gid = blockIdx.x * 256 + threadIdx.x;
    int p = gid >> 4, lane = gid & 15;
    if (p >= L_CNT) return;
    int c = ic[p], d = id[p];
    float4 a = *(const float4*)(zC + (size_t)c * 64 + lane * 4);
    float4 b = *(const float4*)(zD + (size_t)d * 64 + lane * 4);
    float s = a.x * b.x + a.y * b.y + a.z * b.z + a.w * b.w;
    s += __shfl_down(s, 8, 16);
    s += __shfl_down(s, 4, 16);
    s += __shfl_down(s, 2, 16);
    s += __shfl_down(s, 1, 16);
    if (lane == 0) out[p] = fminf(10.0f, fmaxf(-10.0f, s));
}

extern "C" void kernel_launch(void* const* d_in, const int* in_sizes, int n_in,
                              void* d_out, int out_size, void* d_ws, size_t ws_size,
                              hipStream_t stream)
{
    // Persistent node states live in the emb input buffers (harness restores
    // d_in from pristine copies before every timed launch).
    float* xC = (float*)d_in[0];
    float* xD = (float*)d_in[1];
    const float* kW   = (const float*)d_in[2];
    const float* kb   = (const float*)d_in[3];
    const float* qW   = (const float*)d_in[4];
    const float* qb   = (const float*)d_in[5];
    const float* vW   = (const float*)d_in[6];
    const float* vb   = (const float*)d_in[7];
    const float* aW   = (const float*)d_in[8];
    const float* ab   = (const float*)d_in[9];
    const float* skip = (const float*)d_in[10];
    const float* arel = (const float*)d_in[11];
    const float* mrel = (const float*)d_in[12];
    const float* prel = (const float*)d_in[13];
    const float* outW = (const float*)d_in[14];
    const float* outb = (const float*)d_in[15];
    const int* ei_cd  = (const int*)d_in[16];
    const int* ei_dc  = (const int*)d_in[17];
    const int* eli    = (const int*)d_in[18];

    // ---- workspace: 38.5M floats (154MB) + 1.4M ints (5.6MB) ----
    float* ws = (float*)d_ws;
    size_t off = 0;
    float* kv    = ws + off; off += (size_t)NN_ * 256;   // 25.6M  src [k|v]
    float* qo    = ws + off; off += (size_t)NN_ * 128;   // 12.8M  dst q -> attn out
    float* WcatC = ws + off; off += (size_t)129 * 384;
    float* WcatD = ws + off; off += (size_t)129 * 384;
    int* iws = (int*)(ws + off);
    size_t ioff = 0;
    int* rp_cd   = iws + ioff; ioff += NN_ + 1;          // row_ptr (dst=D)
    int* rp_dc   = iws + ioff; ioff += NN_ + 1;          // row_ptr (dst=C)
    int* srcs_cd = iws + ioff; ioff += E_CNT;
    int* srcs_dc = iws + ioff; ioff += E_CNT;
    int* cnt     = iws + ioff; ioff += NN_;              // temp
    int* cursor  = iws + ioff; ioff += NN_;              // temp
    int* partial = iws + ioff; ioff += 128;              // temp
    float* zC = kv;                                      // reuse after edge phases
    float* zD = kv + (size_t)NN_ * 128;

    const int gridM = (NN_ + 63) / 64;            // 1563
    const int gE    = (E_CNT + 255) / 256;        // 1954
    const int gN    = (NN_ + 255) / 256;          // 391
    const int gScan = 98;                         // 98 x 1024 elems
    const int gGath = (NN_ + 3) / 4;              // 4 waves/block

    // ---- build CSR for both relations (edge lists are launch-constant) ----
    {
        const int* srcs[2] = { ei_cd, ei_dc };
        const int* dsts[2] = { ei_cd + E_CNT, ei_dc + E_CNT };
        int* rps[2]  = { rp_cd, rp_dc };
        int* outs[2] = { srcs_cd, srcs_dc };
        for (int r = 0; r < 2; r++) {
            fill0_int<<<gN, 256, 0, stream>>>(cnt, NN_);
            count_dst<<<gE, 256, 0, stream>>>(dsts[r], cnt);
            scan_a<<<gScan, 256, 0, stream>>>(cnt, rps[r], partial);
            scan_b<<<1, 128, 0, stream>>>(partial);
            scan_c<<<gScan, 256, 0, stream>>>(rps[r], partial, cursor);
            scatter_edges<<<gE, 256, 0, stream>>>(srcs[r], dsts[r], cursor, outs[r]);
        }
    }

    for (int l = 0; l < 2; l++) {
        const float* aWl = aW + (size_t)l * 2 * 128 * 128;
        const float* abl = ab + (size_t)l * 2 * 128;

        fuse_weights<<<dim3(129, 2), 384, 0, stream>>>(
            qW + (size_t)l * 2 * 128 * 128, qb + (size_t)l * 2 * 128,
            kW + (size_t)l * 2 * 128 * 128, kb + (size_t)l * 2 * 128,
            vW + (size_t)l * 2 * 128 * 128, vb + (size_t)l * 2 * 128,
            arel + (size_t)l * 2 * NH_ * HD_ * HD_,
            mrel + (size_t)l * 2 * NH_ * HD_ * HD_, WcatC, WcatD);

        // ---- relation 0: C -> D ----
        gemm_tiled<0, 0><<<dim3(gridM, 4), 256, 0, stream>>>(     // kvC = xC @ WcatC[:,128:384]
            xC, 128, WcatC + 128, 384, WcatC + 128 * 384 + 128, kv, 256, NC_, nullptr, nullptr);
        gemm_tiled<0, 0><<<dim3(gridM, 2), 256, 0, stream>>>(     // qD
            xD, 128, WcatD, 384, WcatD + 128 * 384, qo, 128, ND_, nullptr, nullptr);
        attn_gather<<<gGath, 256, 0, stream>>>(rp_cd, srcs_cd, qo, kv,
                                               prel + (l * 2 + 0) * 4, ND_);  // outD in qo

        // kvD from OLD xD (before epilogue D overwrites it)
        gemm_tiled<0, 0><<<dim3(gridM, 4), 256, 0, stream>>>(
            xD, 128, WcatD + 128, 384, WcatD + 128 * 384 + 128, kv, 256, ND_, nullptr, nullptr);

        // epilogue D: xD = relu(g*(gelu(outD)@aW_D+ab_D) + (1-g)*xD)
        gemm_tiled<1, 1><<<dim3(gridM, 2), 256, 0, stream>>>(
            qo, 128, aWl + 128 * 128, 128, abl + 128, xD, 128, ND_, xD, skip + l * 2 + 1);

        // ---- relation 1: D -> C ----
        gemm_tiled<0, 0><<<dim3(gridM, 2), 256, 0, stream>>>(     // qC (old xC)
            xC, 128, WcatC, 384, WcatC + 128 * 384, qo, 128, NC_, nullptr, nullptr);
        attn_gather<<<gGath, 256, 0, stream>>>(rp_dc, srcs_dc, qo, kv,
                                               prel + (l * 2 + 1) * 4, NC_);  // outC in qo

        // epilogue C
        gemm_tiled<1, 1><<<dim3(gridM, 2), 256, 0, stream>>>(
            qo, 128, aWl, 128, abl, xC, 128, NC_, xC, skip + l * 2 + 0);
    }

    // final projections z = x @ outW + outb  ([N,128] @ [128,64])
    gemm_tiled<0, 0><<<dim3(gridM, 1), 256, 0, stream>>>(
        xC, 128, outW, 64, outb, zC, 64, NC_, nullptr, nullptr);
    gemm_tiled<0, 0><<<dim3(gridM, 1), 256, 0, stream>>>(
        xD, 128, outW + 128 * 64, 64, outb + 64, zD, 64, ND_, nullptr, nullptr);

    score_pairs<<<(L_CNT * 16 + 255) / 256, 256, 0, stream>>>(
        eli, eli + L_CNT, zC, zD, (float*)d_out);
}